// Round 1
// baseline (8502.296 us; speedup 1.0000x reference)
//
#include <hip/hip_runtime.h>
#include <math.h>

#define MC      16384
#define NSTEPS  120
#define PER     30
#define NMAT    4
#define NSTR    21
#define WD      50
#define WV      30
#define WE      20
#define RRATE   0.05f

// ws layout (floats)
#define WS_PRPART 0                      // [4][21][2][256] per-block partial sums of pr, pr^2
#define WS_EPART  (NMAT*NSTR*2*256)      // [256] per-block partial sums of e
#define WS_MEANE  (WS_EPART + 256)       // [1]

// out layout (floats), total 32938
#define OUT_PV    0
#define OUT_PVV   84
#define OUT_PEXO  168
#define OUT_MEAN  16552
#define OUT_VAR   16553
#define OUT_ERR   16554

__device__ __forceinline__ float tgridf(int i)  { return (float)((double)i * (1.0/120.0)); }
__device__ __forceinline__ float strikef(int s) { return (float)(0.8 + (double)s * 0.02); }
__device__ __forceinline__ float softplusf(float x){
  // jax.nn.softplus = logaddexp(x, 0) = max(x,0) + log1p(exp(-|x|))
  return fmaxf(x, 0.0f) + log1pf(expf(-fabsf(x)));
}

// hidden layer: acc[j] = relu(b[j] + sum_k hin_lds[k][tid] * W[k*N+j])
// k-loop rolled (dynamic k -> LDS read), j-loop unrolled (acc stays in VGPRs),
// W/b wave-uniform -> scalar loads.
template<int N>
__device__ __forceinline__ void hiddenN(const float* __restrict__ W,
                                        const float* __restrict__ b,
                                        const float* hin, float* acc, int tid){
  #pragma unroll
  for (int j=0;j<N;++j) acc[j]=b[j];
  for (int k=0;k<N;++k){
    float hk = hin[k*64+tid];
    #pragma unroll
    for (int j=0;j<N;++j) acc[j] = fmaf(hk, W[k*N+j], acc[j]);
  }
  #pragma unroll
  for (int j=0;j<N;++j) acc[j]=fmaxf(acc[j],0.0f);
}

template<int N>
__device__ __forceinline__ void commitN(float* lds, const float* acc, int tid){
  #pragma unroll
  for (int j=0;j<N;++j) lds[j*64+tid]=acc[j];
}

// first layer with 2 inputs (t, S); W0 row-major (2,N)
template<int N>
__device__ __forceinline__ void layer0(const float* __restrict__ W0,
                                       const float* __restrict__ b0,
                                       float t0, float S, float* acc){
  #pragma unroll
  for (int j=0;j<N;++j)
    acc[j] = fmaxf(fmaf(t0, W0[j], fmaf(S, W0[N+j], b0[j])), 0.0f);
}

extern "C" __global__ void __launch_bounds__(64,1) mc_main(
    const float* __restrict__ S0p, const float* __restrict__ z,
    const float* __restrict__ dW0, const float* __restrict__ db0,
    const float* __restrict__ dhW, const float* __restrict__ dhb,
    const float* __restrict__ dWo, const float* __restrict__ dbo,
    const float* __restrict__ vW0, const float* __restrict__ vb0,
    const float* __restrict__ vhW, const float* __restrict__ vhb,
    const float* __restrict__ vWo, const float* __restrict__ vbo,
    const float* __restrict__ eW0, const float* __restrict__ eb0,
    const float* __restrict__ ehW, const float* __restrict__ ehb,
    const float* __restrict__ eWo, const float* __restrict__ ebo,
    float* __restrict__ out, float* __restrict__ ws)
{
  __shared__ float ldsA[WD*64];
  __shared__ float ldsB[WD*64];
  __shared__ float rrlds[NMAT*NSTR*64];   // per-lane cv_v partial rows RR[4][21]

  const int tid = threadIdx.x;
  const int m   = blockIdx.x*64 + tid;

  #pragma unroll 4
  for (int q=0;q<NMAT*NSTR;++q) rrlds[q*64+tid]=0.0f;

  const float S0v = S0p[0];
  float S = S0v, runmax = S0v, cvE = 0.0f, C = 0.0f;
  float accE0[WE], accE1[WE], accE2[WE], accE3[WE];  // e-net first-layer path accumulators, all 4 mats
  float G[WV];                                        // per-period v-net factored accumulator
  #pragma unroll
  for (int j=0;j<WE;++j){accE0[j]=0.0f;accE1[j]=0.0f;accE2[j]=0.0f;accE3[j]=0.0f;}
  #pragma unroll
  for (int k=0;k<WV;++k) G[k]=0.0f;

  float acc[WD];

  #pragma unroll 1
  for (int p=0;p<NMAT;++p){
    const float* dW0p=dW0+p*100;  const float* db0p=db0+p*50;
    const float* dhWp=dhW+p*7500; const float* dhbp=dhb+p*150;
    const float* dWop=dWo+p*50;
    const float* vW0p=vW0+p*60;   const float* vb0p=vb0+p*30;
    const float* vhWp=vhW+p*2700; const float* vhbp=vhb+p*90;
    const float* eW0p=eW0+p*2440; const float* eb0p=eb0+p*20;
    const float* ehWp=ehW+p*1200; const float* ehbp=ehb+p*60;
    const float* eWop=eWo+p*20;

    #pragma unroll 1
    for (int ii=1; ii<=PER; ++ii){
      const int i = p*PER + ii;
      const float t0 = tgridf(i-1);
      const float t1 = tgridf(i);
      const float h  = t1 - t0;
      const float sqh= sqrtf(h);
      const float dWn= sqh * z[m*NSTEPS + (i-1)];

      // accE: add path[i-1] = S term (row i of eW0) for all 4 weight sets
      {
        const int roff = i*WE;
        #pragma unroll
        for (int j=0;j<WE;++j){
          accE0[j] = fmaf(S, eW0[0*2440+roff+j], accE0[j]);
          accE1[j] = fmaf(S, eW0[1*2440+roff+j], accE1[j]);
          accE2[j] = fmaf(S, eW0[2*2440+roff+j], accE2[j]);
          accE3[j] = fmaf(S, eW0[3*2440+roff+j], accE3[j]);
        }
      }

      // ---- diffusion net (2 -> 50 -> 50 -> 50 -> 50 -> 1, softplus) ----
      layer0<WD>(dW0p, db0p, t0, S, acc);
      commitN<WD>(ldsA, acc, tid);
      hiddenN<WD>(dhWp,      dhbp,     ldsA, acc, tid); commitN<WD>(ldsB, acc, tid);
      hiddenN<WD>(dhWp+2500, dhbp+50,  ldsB, acc, tid); commitN<WD>(ldsA, acc, tid);
      hiddenN<WD>(dhWp+5000, dhbp+100, ldsA, acc, tid);
      float y = dbo[p];
      #pragma unroll
      for (int k=0;k<WD;++k) y = fmaf(acc[k], dWop[k], y);
      const float diff = softplusf(y);

      const float d1 = 1.0f + RRATE*S*sqh;
      const float d2 = 1.0f + S*diff*sqh;
      const float Snew = S + RRATE*S*h/d1 + S*diff*dWn/d2;
      const float disc = expf(-RRATE*t0);
      const float coef = disc * S * diff * dWn;

      // ---- vanilla net (2 -> 30 -> 30 -> 30 -> 30; last layer factored out) ----
      layer0<WV>(vW0p, vb0p, t0, S, acc);
      commitN<WV>(ldsA, acc, tid);
      hiddenN<WV>(vhWp,      vhbp,    ldsA, acc, tid); commitN<WV>(ldsB, acc, tid);
      hiddenN<WV>(vhWp+900,  vhbp+30, ldsB, acc, tid); commitN<WV>(ldsA, acc, tid);
      hiddenN<WV>(vhWp+1800, vhbp+60, ldsA, acc, tid);
      #pragma unroll
      for (int k=0;k<WV;++k) G[k] = fmaf(coef, acc[k], G[k]);
      C += coef;

      // ---- exotic net (122 -> 20 -> 20 -> 20 -> 20 -> 1) ----
      #pragma unroll
      for (int j=0;j<WE;++j){
        const float aE = (p==0)?accE0[j]:(p==1)?accE1[j]:(p==2)?accE2[j]:accE3[j];
        acc[j] = fmaxf(fmaf(t0, eW0p[j], aE + eb0p[j]), 0.0f);
      }
      commitN<WE>(ldsA, acc, tid);
      hiddenN<WE>(ehWp,     ehbp,    ldsA, acc, tid); commitN<WE>(ldsB, acc, tid);
      hiddenN<WE>(ehWp+400, ehbp+20, ldsB, acc, tid); commitN<WE>(ldsA, acc, tid);
      hiddenN<WE>(ehWp+800, ehbp+40, ldsA, acc, tid);
      float ye = ebo[p];
      #pragma unroll
      for (int k=0;k<WE;++k) ye = fmaf(acc[k], eWop[k], ye);
      cvE = fmaf(coef, ye, cvE);

      runmax = fmaxf(runmax, Snew);

      if (ii==PER){
        // apply factored v-net output layer once per period:
        // RR[mm][s] += G . vWo[p][:, mm*21+s] + C * vbo[p][mm*21+s], for mm >= p
        commitN<WV>(ldsB, G, tid);
        const float* vWop = vWo + p*(WV*NMAT*NSTR);
        const float* vbop = vbo + p*(NMAT*NSTR);
        for (int mm=p; mm<NMAT; ++mm){
          for (int s=0;s<NSTR;++s){
            const int col = mm*NSTR+s;
            float val = C * vbop[col];
            for (int k=0;k<WV;++k) val = fmaf(ldsB[k*64+tid], vWop[k*(NMAT*NSTR)+col], val);
            rrlds[col*64+tid] += val;
          }
        }
        // maturity payoff stats for this period's block
        const float disc_i = expf(-RRATE*t1);
        for (int s=0;s<NSTR;++s){
          const float pr = disc_i*fmaxf(Snew - strikef(s), 0.0f) - rrlds[(p*NSTR+s)*64+tid];
          float sum = pr, ssq = pr*pr;
          for (int o=32;o>0;o>>=1){ sum += __shfl_down(sum,o); ssq += __shfl_down(ssq,o); }
          if (tid==0){
            ws[WS_PRPART + ((p*NSTR+s)*2+0)*256 + blockIdx.x] = sum;
            ws[WS_PRPART + ((p*NSTR+s)*2+1)*256 + blockIdx.x] = ssq;
          }
        }
        #pragma unroll
        for (int k=0;k<WV;++k) G[k]=0.0f;
        C = 0.0f;
      }

      S = Snew;
    }
  }

  const float discT = expf(-RRATE*1.0f);
  const float e  = discT * (runmax - S);
  const float pe = e - cvE;
  out[OUT_PEXO + m] = pe;
  float se = e;
  for (int o=32;o>0;o>>=1) se += __shfl_down(se,o);
  if (tid==0) ws[WS_EPART + blockIdx.x] = se;
}

extern "C" __global__ void fin_pv(const float* __restrict__ ws, float* __restrict__ out){
  const int t = threadIdx.x;
  if (t >= NMAT*NSTR) return;
  float sum=0.0f, ssq=0.0f;
  for (int b=0;b<256;++b){
    sum += ws[WS_PRPART + (t*2+0)*256 + b];
    ssq += ws[WS_PRPART + (t*2+1)*256 + b];
  }
  out[OUT_PV  + t] = sum * (1.0f/MC);
  out[OUT_PVV + t] = (ssq - sum*sum*(1.0f/MC)) * (1.0f/(MC-1));
}

extern "C" __global__ void fin_pe(float* out, float* ws){
  __shared__ float sA[4], sB[4], sC[4];
  const int t = threadIdx.x;
  float sum=0.0f, ssq=0.0f;
  for (int idx=t; idx<MC; idx+=256){
    const float v = out[OUT_PEXO+idx];
    sum += v; ssq = fmaf(v,v,ssq);
  }
  float es = ws[WS_EPART + t];
  for (int o=32;o>0;o>>=1){
    sum += __shfl_down(sum,o);
    ssq += __shfl_down(ssq,o);
    es  += __shfl_down(es,o);
  }
  const int wid=t>>6, lane=t&63;
  if (lane==0){ sA[wid]=sum; sB[wid]=ssq; sC[wid]=es; }
  __syncthreads();
  if (t==0){
    const float s=sA[0]+sA[1]+sA[2]+sA[3];
    const float q=sB[0]+sB[1]+sB[2]+sB[3];
    const float e=sC[0]+sC[1]+sC[2]+sC[3];
    out[OUT_MEAN]=s*(1.0f/MC);
    out[OUT_VAR]=(q - s*s*(1.0f/MC))*(1.0f/(MC-1));
    ws[WS_MEANE]=e*(1.0f/MC);
  }
}

extern "C" __global__ void fin_err(float* out, const float* __restrict__ ws){
  const int m = blockIdx.x*blockDim.x + threadIdx.x;
  if (m < MC) out[OUT_ERR+m] = out[OUT_PEXO+m] - ws[WS_MEANE];
}

extern "C" void kernel_launch(void* const* d_in, const int* in_sizes, int n_in,
                              void* d_out, int out_size, void* d_ws, size_t ws_size,
                              hipStream_t stream){
  (void)in_sizes; (void)n_in; (void)out_size; (void)ws_size;
  const float* S0 =(const float*)d_in[0];
  const float* z  =(const float*)d_in[1];
  const float* dW0=(const float*)d_in[2];
  const float* db0=(const float*)d_in[3];
  const float* dhW=(const float*)d_in[4];
  const float* dhb=(const float*)d_in[5];
  const float* dWo=(const float*)d_in[6];
  const float* dbo=(const float*)d_in[7];
  const float* vW0=(const float*)d_in[8];
  const float* vb0=(const float*)d_in[9];
  const float* vhW=(const float*)d_in[10];
  const float* vhb=(const float*)d_in[11];
  const float* vWo=(const float*)d_in[12];
  const float* vbo=(const float*)d_in[13];
  const float* eW0=(const float*)d_in[14];
  const float* eb0=(const float*)d_in[15];
  const float* ehW=(const float*)d_in[16];
  const float* ehb=(const float*)d_in[17];
  const float* eWo=(const float*)d_in[18];
  const float* ebo=(const float*)d_in[19];
  float* out=(float*)d_out;
  float* ws =(float*)d_ws;

  mc_main<<<dim3(256),dim3(64),0,stream>>>(S0,z,dW0,db0,dhW,dhb,dWo,dbo,
                                           vW0,vb0,vhW,vhb,vWo,vbo,
                                           eW0,eb0,ehW,ehb,eWo,ebo,out,ws);
  fin_pv <<<dim3(1), dim3(128),0,stream>>>(ws,out);
  fin_pe <<<dim3(1), dim3(256),0,stream>>>(out,ws);
  fin_err<<<dim3(64),dim3(256),0,stream>>>(out,ws);
}

// Round 2
// 2302.504 us; speedup vs baseline: 3.6926x; 3.6926x over previous
//
#include <hip/hip_runtime.h>
#include <math.h>

#define MC      16384
#define NSTEPS  120
#define PER     30
#define NMAT    4
#define NSTR    21
#define WD      50
#define WV      30
#define WE      20
#define RRATE   0.05f
#define NW      8

// per-wave output-row counts (8 waves, overlapping-clamp split)
#define JND 7
#define JNV 4
#define JNE 3

// ws layout (floats)
#define WS_PRPART 0                      // [4][21][2][256] per-block partial sums of pr, pr^2
#define WS_EPART  (NMAT*NSTR*2*256)      // [256] per-block partial sums of e
#define WS_MEANE  (WS_EPART + 256)       // [1]

// out layout (floats)
#define OUT_PV    0
#define OUT_PVV   84
#define OUT_PEXO  168
#define OUT_MEAN  16552
#define OUT_VAR   16553
#define OUT_ERR   16554

__device__ __forceinline__ float tgridf(int i)  { return (float)((double)i * (1.0/120.0)); }
__device__ __forceinline__ float strikef(int s) { return (float)(0.8 + (double)s * 0.02); }
__device__ __forceinline__ float softplusf(float x){
  return fmaxf(x, 0.0f) + log1pf(expf(-fabsf(x)));
}

// hidden layer, feature-split: acc[j] = relu(b[j0+j] + sum_k hin[k][lane] * W[k][j0+j])
// k fully unrolled -> ds_read_b32 with immediate offsets; weights uniform -> s_load.
template<int N, int JN>
__device__ __forceinline__ void hiddenS(const float* __restrict__ W,
                                        const float* __restrict__ b,
                                        const float* hin, float* acc,
                                        int lane, int j0){
  #pragma unroll
  for (int j=0;j<JN;++j) acc[j]=b[j0+j];
  #pragma unroll
  for (int k=0;k<N;++k){
    const float hk = hin[k*64+lane];
    #pragma unroll
    for (int j=0;j<JN;++j) acc[j] = fmaf(hk, W[k*N+j0+j], acc[j]);
  }
  #pragma unroll
  for (int j=0;j<JN;++j) acc[j]=fmaxf(acc[j],0.0f);
}

template<int JN>
__device__ __forceinline__ void commitS(float* lds, const float* acc, int lane, int j0){
  #pragma unroll
  for (int j=0;j<JN;++j) lds[(j0+j)*64+lane]=acc[j];
}

template<int N, int JN>
__device__ __forceinline__ void layer0S(const float* __restrict__ W0,
                                        const float* __restrict__ b0,
                                        float t0, float S, float* acc, int j0){
  #pragma unroll
  for (int j=0;j<JN;++j)
    acc[j] = fmaxf(fmaf(t0, W0[j0+j], fmaf(S, W0[N+j0+j], b0[j0+j])), 0.0f);
}

extern "C" __global__ void __launch_bounds__(512,1) mc_main(
    const float* __restrict__ S0p, const float* __restrict__ z,
    const float* __restrict__ dW0, const float* __restrict__ db0,
    const float* __restrict__ dhW, const float* __restrict__ dhb,
    const float* __restrict__ dWo, const float* __restrict__ dbo,
    const float* __restrict__ vW0, const float* __restrict__ vb0,
    const float* __restrict__ vhW, const float* __restrict__ vhb,
    const float* __restrict__ vWo, const float* __restrict__ vbo,
    const float* __restrict__ eW0, const float* __restrict__ eb0,
    const float* __restrict__ ehW, const float* __restrict__ ehb,
    const float* __restrict__ eWo, const float* __restrict__ ebo,
    float* __restrict__ out, float* __restrict__ ws)
{
  __shared__ float A[WD*64];
  __shared__ float B[WD*64];
  __shared__ float rr[NMAT*NSTR*64];

  const int tid  = threadIdx.x;
  const int lane = tid & 63;
  const int wid  = __builtin_amdgcn_readfirstlane(tid >> 6);
  const int m    = blockIdx.x*64 + lane;

  for (int q=tid; q<NMAT*NSTR*64; q+=512) rr[q]=0.0f;

  // clamped overlapping feature splits (uniform per wave)
  const int j0d = min(JND*wid, WD-JND);
  const int j0v = min(JNV*wid, WV-JNV);
  const int j0e = min(JNE*wid, WE-JNE);

  const float S0v = S0p[0];
  float S = S0v, runmax = S0v, cvE = 0.0f, C = 0.0f;
  float G[JNV];
  float aE0[JNE], aE1[JNE], aE2[JNE], aE3[JNE];
  #pragma unroll
  for (int j=0;j<JNV;++j) G[j]=0.0f;
  #pragma unroll
  for (int j=0;j<JNE;++j){aE0[j]=0.0f;aE1[j]=0.0f;aE2[j]=0.0f;aE3[j]=0.0f;}

  float acc[JND];

  #pragma unroll 1
  for (int p=0;p<NMAT;++p){
    const float* dW0p=dW0+p*100;  const float* db0p=db0+p*50;
    const float* dhWp=dhW+p*7500; const float* dhbp=dhb+p*150;
    const float* dWop=dWo+p*50;
    const float* vW0p=vW0+p*60;   const float* vb0p=vb0+p*30;
    const float* vhWp=vhW+p*2700; const float* vhbp=vhb+p*90;
    const float* vWop=vWo+p*2520; const float* vbop=vbo+p*84;
    const float* eW0p=eW0+p*2440; const float* eb0p=eb0+p*20;
    const float* ehWp=ehW+p*1200; const float* ehbp=ehb+p*60;
    const float* eWop=eWo+p*20;

    #pragma unroll 1
    for (int ii=1; ii<=PER; ++ii){
      const int i  = p*PER + ii;
      const float t0 = tgridf(i-1);
      const float t1 = tgridf(i);
      const float h  = t1 - t0;
      const float sqh= sqrtf(h);
      const float dWn= sqh * z[m*NSTEPS + (i-1)];

      __syncthreads();   // protect A writes below vs prev-step ye reads of A

      // accE update: add path[i-1]=S against row i of eW0, all 4 mats, own j-slice
      {
        const int roff = i*WE + j0e;
        #pragma unroll
        for (int j=0;j<JNE;++j){
          aE0[j] = fmaf(S, eW0[      roff+j], aE0[j]);
          aE1[j] = fmaf(S, eW0[2440+ roff+j], aE1[j]);
          aE2[j] = fmaf(S, eW0[4880+ roff+j], aE2[j]);
          aE3[j] = fmaf(S, eW0[7320+ roff+j], aE3[j]);
        }
      }

      // ---- diffusion net (2 -> 50 x3 -> 1, softplus) ----
      layer0S<WD,JND>(dW0p, db0p, t0, S, acc, j0d); commitS<JND>(A, acc, lane, j0d);
      __syncthreads();
      hiddenS<WD,JND>(dhWp,      dhbp,     A, acc, lane, j0d); commitS<JND>(B, acc, lane, j0d);
      __syncthreads();
      hiddenS<WD,JND>(dhWp+2500, dhbp+50,  B, acc, lane, j0d); commitS<JND>(A, acc, lane, j0d);
      __syncthreads();
      hiddenS<WD,JND>(dhWp+5000, dhbp+100, A, acc, lane, j0d); commitS<JND>(B, acc, lane, j0d);
      __syncthreads();
      float y = dbo[p];
      #pragma unroll
      for (int k=0;k<WD;++k) y = fmaf(B[k*64+lane], dWop[k], y);   // redundant in all waves
      const float diff = softplusf(y);

      const float d1 = 1.0f + RRATE*S*sqh;
      const float d2 = 1.0f + S*diff*sqh;
      const float Snew = S + RRATE*S*h/d1 + S*diff*dWn/d2;
      const float disc = expf(-RRATE*t0);
      const float coef = disc * S * diff * dWn;

      // ---- vanilla net (2 -> 30 x3; output layer factored into G,C) ----
      layer0S<WV,JNV>(vW0p, vb0p, t0, S, acc, j0v); commitS<JNV>(A, acc, lane, j0v);
      __syncthreads();   // also guarantees all waves finished y-reads of B
      hiddenS<WV,JNV>(vhWp,      vhbp,    A, acc, lane, j0v); commitS<JNV>(B, acc, lane, j0v);
      __syncthreads();
      hiddenS<WV,JNV>(vhWp+900,  vhbp+30, B, acc, lane, j0v); commitS<JNV>(A, acc, lane, j0v);
      __syncthreads();
      hiddenS<WV,JNV>(vhWp+1800, vhbp+60, A, acc, lane, j0v);   // stays in regs
      #pragma unroll
      for (int j=0;j<JNV;++j) G[j] = fmaf(coef, acc[j], G[j]);
      C += coef;

      // ---- exotic net (122 -> 20 x3 -> 1) ----
      #pragma unroll
      for (int j=0;j<JNE;++j){
        const float aE = (p==0)?aE0[j]:(p==1)?aE1[j]:(p==2)?aE2[j]:aE3[j];
        acc[j] = fmaxf(fmaf(t0, eW0p[j0e+j], aE + eb0p[j0e+j]), 0.0f);
      }
      commitS<JNE>(B, acc, lane, j0e);
      __syncthreads();   // all waves finished v-h3 reads of A
      hiddenS<WE,JNE>(ehWp,     ehbp,    B, acc, lane, j0e); commitS<JNE>(A, acc, lane, j0e);
      __syncthreads();
      hiddenS<WE,JNE>(ehWp+400, ehbp+20, A, acc, lane, j0e); commitS<JNE>(B, acc, lane, j0e);
      __syncthreads();
      hiddenS<WE,JNE>(ehWp+800, ehbp+40, B, acc, lane, j0e); commitS<JNE>(A, acc, lane, j0e);
      __syncthreads();
      float ye = ebo[p];
      #pragma unroll
      for (int k=0;k<WE;++k) ye = fmaf(A[k*64+lane], eWop[k], ye);  // redundant
      cvE = fmaf(coef, ye, cvE);

      runmax = fmaxf(runmax, Snew);

      if (ii==PER){
        // G -> LDS (B rows 0..29), then factored v output layer into rr
        commitS<JNV>(B, G, lane, j0v);
        __syncthreads();
        float Greg[WV];
        #pragma unroll
        for (int k=0;k<WV;++k) Greg[k]=B[k*64+lane];
        const int c0=(NMAT*NSTR*wid)/NW, c1=(NMAT*NSTR*(wid+1))/NW;
        for (int c=c0;c<c1;++c){
          if (c >= p*NSTR){
            float val = C * vbop[c];
            #pragma unroll
            for (int k=0;k<WV;++k) val = fmaf(Greg[k], vWop[k*(NMAT*NSTR)+c], val);
            rr[c*64+lane] += val;
          }
        }
        __syncthreads();
        const float disc_i = expf(-RRATE*t1);
        for (int s=wid; s<NSTR; s+=NW){
          const float pr = disc_i*fmaxf(Snew - strikef(s), 0.0f) - rr[(p*NSTR+s)*64+lane];
          float sum = pr, ssq = pr*pr;
          for (int o=32;o>0;o>>=1){ sum += __shfl_down(sum,o); ssq += __shfl_down(ssq,o); }
          if (lane==0){
            ws[WS_PRPART + ((p*NSTR+s)*2+0)*256 + blockIdx.x] = sum;
            ws[WS_PRPART + ((p*NSTR+s)*2+1)*256 + blockIdx.x] = ssq;
          }
        }
        #pragma unroll
        for (int j=0;j<JNV;++j) G[j]=0.0f;
        C = 0.0f;
      }

      S = Snew;
    }
  }

  if (wid==0){
    const float discT = expf(-RRATE*1.0f);
    const float e  = discT * (runmax - S);
    const float pe = e - cvE;
    out[OUT_PEXO + m] = pe;
    float se = e;
    for (int o=32;o>0;o>>=1) se += __shfl_down(se,o);
    if (lane==0) ws[WS_EPART + blockIdx.x] = se;
  }
}

extern "C" __global__ void fin_pv(const float* __restrict__ ws, float* __restrict__ out){
  const int t = threadIdx.x;
  if (t >= NMAT*NSTR) return;
  float sum=0.0f, ssq=0.0f;
  for (int b=0;b<256;++b){
    sum += ws[WS_PRPART + (t*2+0)*256 + b];
    ssq += ws[WS_PRPART + (t*2+1)*256 + b];
  }
  out[OUT_PV  + t] = sum * (1.0f/MC);
  out[OUT_PVV + t] = (ssq - sum*sum*(1.0f/MC)) * (1.0f/(MC-1));
}

extern "C" __global__ void fin_pe(float* out, float* ws){
  __shared__ float sA[4], sB[4], sC[4];
  const int t = threadIdx.x;
  float sum=0.0f, ssq=0.0f;
  for (int idx=t; idx<MC; idx+=256){
    const float v = out[OUT_PEXO+idx];
    sum += v; ssq = fmaf(v,v,ssq);
  }
  float es = ws[WS_EPART + t];
  for (int o=32;o>0;o>>=1){
    sum += __shfl_down(sum,o);
    ssq += __shfl_down(ssq,o);
    es  += __shfl_down(es,o);
  }
  const int wid=t>>6, lane=t&63;
  if (lane==0){ sA[wid]=sum; sB[wid]=ssq; sC[wid]=es; }
  __syncthreads();
  if (t==0){
    const float s=sA[0]+sA[1]+sA[2]+sA[3];
    const float q=sB[0]+sB[1]+sB[2]+sB[3];
    const float e=sC[0]+sC[1]+sC[2]+sC[3];
    out[OUT_MEAN]=s*(1.0f/MC);
    out[OUT_VAR]=(q - s*s*(1.0f/MC))*(1.0f/(MC-1));
    ws[WS_MEANE]=e*(1.0f/MC);
  }
}

extern "C" __global__ void fin_err(float* out, const float* __restrict__ ws){
  const int m = blockIdx.x*blockDim.x + threadIdx.x;
  if (m < MC) out[OUT_ERR+m] = out[OUT_PEXO+m] - ws[WS_MEANE];
}

extern "C" void kernel_launch(void* const* d_in, const int* in_sizes, int n_in,
                              void* d_out, int out_size, void* d_ws, size_t ws_size,
                              hipStream_t stream){
  (void)in_sizes; (void)n_in; (void)out_size; (void)ws_size;
  const float* S0 =(const float*)d_in[0];
  const float* z  =(const float*)d_in[1];
  const float* dW0=(const float*)d_in[2];
  const float* db0=(const float*)d_in[3];
  const float* dhW=(const float*)d_in[4];
  const float* dhb=(const float*)d_in[5];
  const float* dWo=(const float*)d_in[6];
  const float* dbo=(const float*)d_in[7];
  const float* vW0=(const float*)d_in[8];
  const float* vb0=(const float*)d_in[9];
  const float* vhW=(const float*)d_in[10];
  const float* vhb=(const float*)d_in[11];
  const float* vWo=(const float*)d_in[12];
  const float* vbo=(const float*)d_in[13];
  const float* eW0=(const float*)d_in[14];
  const float* eb0=(const float*)d_in[15];
  const float* ehW=(const float*)d_in[16];
  const float* ehb=(const float*)d_in[17];
  const float* eWo=(const float*)d_in[18];
  const float* ebo=(const float*)d_in[19];
  float* out=(float*)d_out;
  float* ws =(float*)d_ws;

  mc_main<<<dim3(256),dim3(512),0,stream>>>(S0,z,dW0,db0,dhW,dhb,dWo,dbo,
                                            vW0,vb0,vhW,vhb,vWo,vbo,
                                            eW0,eb0,ehW,ehb,eWo,ebo,out,ws);
  fin_pv <<<dim3(1), dim3(128),0,stream>>>(ws,out);
  fin_pe <<<dim3(1), dim3(256),0,stream>>>(out,ws);
  fin_err<<<dim3(64),dim3(256),0,stream>>>(out,ws);
}

// Round 3
// 569.781 us; speedup vs baseline: 14.9220x; 4.0410x over previous
//
#include <hip/hip_runtime.h>
#include <math.h>

#define MC      16384
#define NSTEPS  120
#define PER     30
#define NMAT    4
#define NSTR    21
#define RRATE   0.05f

typedef short  short8  __attribute__((ext_vector_type(8)));
typedef short  short4v __attribute__((ext_vector_type(4)));
typedef float  f32x4   __attribute__((ext_vector_type(4)));

// ws layout (floats) — same as round 2
#define WS_PRPART 0
#define WS_EPART  (NMAT*NSTR*2*256)
#define WS_MEANE  (WS_EPART + 256)

// out layout (floats)
#define OUT_PV    0
#define OUT_PVV   84
#define OUT_PEXO  168
#define OUT_MEAN  16552
#define OUT_VAR   16553
#define OUT_ERR   16554

__device__ __forceinline__ float tgridf(int i)  { return (float)((double)i * (1.0/120.0)); }
__device__ __forceinline__ float strikef(int s) { return (float)(0.8 + (double)s * 0.02); }
__device__ __forceinline__ float softplusf(float x){
  return fmaxf(x, 0.0f) + log1pf(expf(-fabsf(x)));
}
// f32 -> bf16 bits (RTNE)
__device__ __forceinline__ unsigned short f2bf(float f){
  unsigned u = __builtin_bit_cast(unsigned, f);
  unsigned r = (u + 0x7FFFu + ((u>>16)&1u)) >> 16;
  return (unsigned short)r;
}
// swizzled byte address in a [64 rows x 64 cols] bf16 LDS tile (row stride 128B).
// slot = 16B chunk index within row (0..7); swizzle: slot' = (slot+row)&7.
__device__ __forceinline__ int swaddr(int row, int slot, int inner){
  return row*128 + (((slot + row) & 7) << 4) + inner;
}
// A-fragment read: lane l -> A[mt*16 + (l&15)][32*ktbase/4... base*8 + 8*(l>>4) + i]
__device__ __forceinline__ short8 rdA(const unsigned short* H, int mt, int base, int lane){
  int addr = swaddr(mt*16 + (lane&15), base + (lane>>4), 0);
  return *(const short8*)((const char*)H + addr);
}
__device__ __forceinline__ f32x4 mm(short8 a, short8 b, f32x4 c){
  return __builtin_amdgcn_mfma_f32_16x16x32_bf16(a, b, c, 0, 0, 0);
}
// D-store (+bias, optional relu) into swizzled tile at column base colbase.
__device__ __forceinline__ void stD(unsigned short* H, int colbase, int mt, int lane,
                                    f32x4 acc, float bias, bool relu){
  int col  = colbase + (lane & 15);
  int slot = col >> 3, inner = (col & 7)*2;
  #pragma unroll
  for (int i2=0;i2<4;++i2){
    int r = mt*16 + ((lane>>4)<<2) + i2;
    float v = acc[i2] + bias;
    if (relu) v = fmaxf(v, 0.0f);
    *(unsigned short*)((char*)H + swaddr(r, slot, inner)) = f2bf(v);
  }
}
// B-fragment build from row-major W[k][n] (ld = ldn), valid k<KV, n<NV.
__device__ __forceinline__ short8 mkB(const float* __restrict__ W, int ldn, int KV, int NV,
                                      int kt, int n0, int lane){
  short8 r;
  #pragma unroll
  for (int i2=0;i2<8;++i2){
    int k = kt*32 + ((lane>>4)<<3) + i2;
    int n = n0 + (lane & 15);
    float w = (k<KV && n<NV) ? W[k*ldn + n] : 0.0f;
    r[i2] = (short)f2bf(w);
  }
  return r;
}
// B-fragment for an output VECTOR w[k], replicated across all 16 cols.
__device__ __forceinline__ short8 mkBvec(const float* __restrict__ W, int KV, int kt, int lane){
  short8 r;
  #pragma unroll
  for (int i2=0;i2<8;++i2){
    int k = kt*32 + ((lane>>4)<<3) + i2;
    r[i2] = (short)((k<KV) ? f2bf(W[k]) : 0);
  }
  return r;
}

extern "C" __global__ void __launch_bounds__(512,1) mc_main(
    const float* __restrict__ S0p, const float* __restrict__ z,
    const float* __restrict__ dW0, const float* __restrict__ db0,
    const float* __restrict__ dhW, const float* __restrict__ dhb,
    const float* __restrict__ dWo, const float* __restrict__ dbo,
    const float* __restrict__ vW0, const float* __restrict__ vb0,
    const float* __restrict__ vhW, const float* __restrict__ vhb,
    const float* __restrict__ vWo, const float* __restrict__ vbo,
    const float* __restrict__ eW0, const float* __restrict__ eb0,
    const float* __restrict__ ehW, const float* __restrict__ ehb,
    const float* __restrict__ eWo, const float* __restrict__ ebo,
    float* __restrict__ out, float* __restrict__ ws)
{
  __shared__ unsigned short Hb0[64*64];     // swizzled bf16 activation tile (ping)
  __shared__ unsigned short Hb1[64*64];     // (pong)
  __shared__ float accEl[NMAT*64*21];       // e-net first-layer path accumulators (stride 21: bank-friendly)
  __shared__ float yb[64], yeb[64], coefb[64], Cb[64], Sb[64];
  __shared__ float part[NMAT*NSTR*2];

  const int tid  = threadIdx.x;
  const int lane = tid & 63;
  const int wid  = __builtin_amdgcn_readfirstlane(tid >> 6);
  const int m    = blockIdx.x*64 + lane;

  for (int q=tid; q<NMAT*64*21; q+=512) accEl[q]=0.0f;

  // wave -> tile assignment
  const int ntd  = wid & 3;            // d-net: N-tile; m-tiles {mtd0, mtd0+1}
  const int mtd0 = (wid >> 2) * 2;
  const int mtv  = wid & 3;            // v-net & e-net tile (mtv, ntv)
  const int ntv  = wid >> 2;

  const float S0v = S0p[0];
  float S = S0v, runmax = S0v, cvE = 0.0f, C = 0.0f, coef = 0.0f;
  f32x4 G = {0.f,0.f,0.f,0.f};
  f32x4 rr[3]; 
  #pragma unroll
  for (int q=0;q<3;++q){ rr[q][0]=0.f; rr[q][1]=0.f; rr[q][2]=0.f; rr[q][3]=0.f; }

  __syncthreads();

  #pragma unroll 1
  for (int p=0;p<NMAT;++p){
    const float* dW0p = dW0 + p*100;  const float* db0p = db0 + p*50;
    const float* vW0p = vW0 + p*60;   const float* vb0p = vb0 + p*30;
    const float* eW00p= eW0 + p*2440; const float* eb0p = eb0 + p*20;
    const float* vWop = vWo + p*2520; const float* vbop = vbo + p*84;
    const float  dboS = dbo[p],  eboS = ebo[p];

    // ---- per-period weight fragments (bf16, VGPR-resident) ----
    const int nd = ntd*16 + (lane&15);
    const int nv = ntv*16 + (lane&15);
    short8 Bd00 = mkB(dhW + p*7500 +    0, 50, 50, 50, 0, ntd*16, lane);
    short8 Bd01 = mkB(dhW + p*7500 +    0, 50, 50, 50, 1, ntd*16, lane);
    short8 Bd10 = mkB(dhW + p*7500 + 2500, 50, 50, 50, 0, ntd*16, lane);
    short8 Bd11 = mkB(dhW + p*7500 + 2500, 50, 50, 50, 1, ntd*16, lane);
    short8 Bd20 = mkB(dhW + p*7500 + 5000, 50, 50, 50, 0, ntd*16, lane);
    short8 Bd21 = mkB(dhW + p*7500 + 5000, 50, 50, 50, 1, ntd*16, lane);
    float biasD0 = (nd<50)? dhb[p*150 +      nd] : 0.f;
    float biasD1 = (nd<50)? dhb[p*150 + 50 + nd] : 0.f;
    float biasD2 = (nd<50)? dhb[p*150 +100 + nd] : 0.f;
    short8 WoD0 = mkBvec(dWo + p*50, 50, 0, lane);
    short8 WoD1 = mkBvec(dWo + p*50, 50, 1, lane);
    short8 Bv0 = mkB(vhW + p*2700 +    0, 30, 30, 30, 0, ntv*16, lane);
    short8 Bv1 = mkB(vhW + p*2700 +  900, 30, 30, 30, 0, ntv*16, lane);
    short8 Bv2 = mkB(vhW + p*2700 + 1800, 30, 30, 30, 0, ntv*16, lane);
    float biasV0 = (nv<30)? vhb[p*90 +      nv] : 0.f;
    float biasV1 = (nv<30)? vhb[p*90 + 30 + nv] : 0.f;
    float biasV2 = (nv<30)? vhb[p*90 + 60 + nv] : 0.f;
    short8 Be0 = mkB(ehW + p*1200 +   0, 20, 20, 20, 0, ntv*16, lane);
    short8 Be1 = mkB(ehW + p*1200 + 400, 20, 20, 20, 0, ntv*16, lane);
    short8 Be2 = mkB(ehW + p*1200 + 800, 20, 20, 20, 0, ntv*16, lane);
    float biasE0 = (nv<20)? ehb[p*60 +      nv] : 0.f;
    float biasE1 = (nv<20)? ehb[p*60 + 20 + nv] : 0.f;
    float biasE2 = (nv<20)? ehb[p*60 + 40 + nv] : 0.f;
    short8 WoE = mkBvec(eWo + p*20, 20, 0, lane);

    #pragma unroll 1
    for (int ii=1; ii<=PER; ++ii){
      const int i   = p*PER + ii;
      const float t0  = tgridf(i-1);
      const float t1  = tgridf(i);
      const float h   = t1 - t0;
      const float sqh = sqrtf(h);

      // ---- phase 0: accE update (uses S = path[i-1]) + d-net H0 -> Hb0 ----
      {
        const float* erow = eW0 + (wid>>1)*2440 + i*20 + (wid&1)*10;
        float* aE = accEl + ((wid>>1)*64 + lane)*21 + (wid&1)*10;
        #pragma unroll
        for (int jj=0;jj<10;++jj) aE[jj] = fmaf(S, erow[jj], aE[jj]);
      }
      {
        const int j0 = wid*8;
        short8 hv;
        #pragma unroll
        for (int jj=0;jj<8;++jj){
          int j = j0+jj;
          float u = (j<50) ? fmaxf(fmaf(S, dW0p[50+j], fmaf(t0, dW0p[j], db0p[j])), 0.f) : 0.f;
          hv[jj] = (short)f2bf(u);
        }
        *(short8*)((char*)Hb0 + swaddr(lane, wid, 0)) = hv;
      }
      __syncthreads();
      // ---- phase 1: d-L1  Hb0 -> Hb1 ----
      {
        short8 a00=rdA(Hb0,mtd0,0,lane), a01=rdA(Hb0,mtd0,4,lane);
        short8 a10=rdA(Hb0,mtd0+1,0,lane), a11=rdA(Hb0,mtd0+1,4,lane);
        f32x4 c0={0.f,0.f,0.f,0.f}, c1={0.f,0.f,0.f,0.f};
        c0=mm(a00,Bd00,c0); c0=mm(a01,Bd01,c0);
        c1=mm(a10,Bd00,c1); c1=mm(a11,Bd01,c1);
        stD(Hb1, ntd*16, mtd0,   lane, c0, biasD0, true);
        stD(Hb1, ntd*16, mtd0+1, lane, c1, biasD0, true);
      }
      __syncthreads();
      // ---- phase 2: d-L2  Hb1 -> Hb0 ----
      {
        short8 a00=rdA(Hb1,mtd0,0,lane), a01=rdA(Hb1,mtd0,4,lane);
        short8 a10=rdA(Hb1,mtd0+1,0,lane), a11=rdA(Hb1,mtd0+1,4,lane);
        f32x4 c0={0.f,0.f,0.f,0.f}, c1={0.f,0.f,0.f,0.f};
        c0=mm(a00,Bd10,c0); c0=mm(a01,Bd11,c0);
        c1=mm(a10,Bd10,c1); c1=mm(a11,Bd11,c1);
        stD(Hb0, ntd*16, mtd0,   lane, c0, biasD1, true);
        stD(Hb0, ntd*16, mtd0+1, lane, c1, biasD1, true);
      }
      __syncthreads();
      // ---- phase 3: d-L3  Hb0 -> Hb1 ----
      {
        short8 a00=rdA(Hb0,mtd0,0,lane), a01=rdA(Hb0,mtd0,4,lane);
        short8 a10=rdA(Hb0,mtd0+1,0,lane), a11=rdA(Hb0,mtd0+1,4,lane);
        f32x4 c0={0.f,0.f,0.f,0.f}, c1={0.f,0.f,0.f,0.f};
        c0=mm(a00,Bd20,c0); c0=mm(a01,Bd21,c0);
        c1=mm(a10,Bd20,c1); c1=mm(a11,Bd21,c1);
        stD(Hb1, ntd*16, mtd0,   lane, c0, biasD2, true);
        stD(Hb1, ntd*16, mtd0+1, lane, c1, biasD2, true);
      }
      __syncthreads();
      // ---- phase 4: y = h3 . dWo (waves 0-3, MFMA with replicated Wo cols) ----
      if (wid < 4){
        short8 a0=rdA(Hb1,wid,0,lane), a1=rdA(Hb1,wid,4,lane);
        f32x4 c={0.f,0.f,0.f,0.f};
        c=mm(a0,WoD0,c); c=mm(a1,WoD1,c);
        if ((lane&15)==0){
          int g = lane>>4;
          #pragma unroll
          for (int i2=0;i2<4;++i2) yb[wid*16 + g*4 + i2] = c[i2];
        }
      }
      __syncthreads();
      // ---- phase 5: per-sample scalars + e-H0 (Hb0 cols 0..31) + v-H0 (cols 32..63) ----
      {
        float y    = yb[lane] + dboS;
        float diff = softplusf(y);
        float dWn  = sqh * z[(size_t)m*NSTEPS + (i-1)];
        float d1 = 1.0f + RRATE*S*sqh;
        float d2 = 1.0f + S*diff*sqh;
        float Snew = S + RRATE*S*h/d1 + S*diff*dWn/d2;
        float disc = expf(-RRATE*t0);
        coef = disc * S * diff * dWn;
        if (wid==0) coefb[lane] = coef;
        C += coef;
        runmax = fmaxf(runmax, Snew);
        {
          const int j0 = 4*wid;
          const float* aE = accEl + (p*64 + lane)*21;
          short4v hv;
          #pragma unroll
          for (int jj=0;jj<4;++jj){
            int j = j0+jj;
            float u = (j<20) ? fmaxf(t0*eW00p[j] + aE[j] + eb0p[j], 0.f) : 0.f;
            hv[jj] = (short)f2bf(u);
          }
          *(short4v*)((char*)Hb0 + swaddr(lane, (j0>>3), (j0&7)*2)) = hv;
        }
        {
          const int j0 = 4*wid;
          short4v hv;
          #pragma unroll
          for (int jj=0;jj<4;++jj){
            int j = j0+jj;
            float u = (j<30) ? fmaxf(fmaf(S, vW0p[30+j], fmaf(t0, vW0p[j], vb0p[j])), 0.f) : 0.f;
            hv[jj] = (short)f2bf(u);
          }
          *(short4v*)((char*)Hb0 + swaddr(lane, 4+(j0>>3), (j0&7)*2)) = hv;
        }
        S = Snew;   // H0 inputs above used S_old
      }
      __syncthreads();
      // ---- phase 6: e-L1 (Hb0 base0 -> Hb1 cols 32+), v-L1 (Hb0 base4 -> Hb1 cols 0..31) ----
      {
        short8 ae=rdA(Hb0,mtv,0,lane); f32x4 ce={0.f,0.f,0.f,0.f}; ce=mm(ae,Be0,ce);
        stD(Hb1, 32+ntv*16, mtv, lane, ce, biasE0, true);
        short8 av=rdA(Hb0,mtv,4,lane); f32x4 cv={0.f,0.f,0.f,0.f}; cv=mm(av,Bv0,cv);
        stD(Hb1, ntv*16, mtv, lane, cv, biasV0, true);
      }
      __syncthreads();
      // ---- phase 7: v-L2 (Hb1 base0 -> Hb0 cols 0..31), e-L2 (Hb1 base4 -> Hb0 cols 32+) ----
      {
        short8 av=rdA(Hb1,mtv,0,lane); f32x4 cv={0.f,0.f,0.f,0.f}; cv=mm(av,Bv1,cv);
        stD(Hb0, ntv*16, mtv, lane, cv, biasV1, true);
        short8 ae=rdA(Hb1,mtv,4,lane); f32x4 ce={0.f,0.f,0.f,0.f}; ce=mm(ae,Be1,ce);
        stD(Hb0, 32+ntv*16, mtv, lane, ce, biasE1, true);
      }
      __syncthreads();
      // ---- phase 8: v-L3 -> G accumulate (regs); e-L3 -> Hb1 cols 32+ ----
      {
        short8 av=rdA(Hb0,mtv,0,lane); f32x4 cv={0.f,0.f,0.f,0.f}; cv=mm(av,Bv2,cv);
        #pragma unroll
        for (int i2=0;i2<4;++i2){
          int r = mtv*16 + ((lane>>4)<<2) + i2;
          float hv = fmaxf(cv[i2] + biasV2, 0.f);
          G[i2] = fmaf(coefb[r], hv, G[i2]);
        }
        short8 ae=rdA(Hb0,mtv,4,lane); f32x4 ce={0.f,0.f,0.f,0.f}; ce=mm(ae,Be2,ce);
        stD(Hb1, 32+ntv*16, mtv, lane, ce, biasE2, true);
      }
      __syncthreads();
      // ---- phase 9: ye = e-h3 . eWo (waves 4-7) ----
      if (wid >= 4){
        int mt = wid & 3;
        short8 a=rdA(Hb1,mt,4,lane);
        f32x4 c={0.f,0.f,0.f,0.f};
        c=mm(a,WoE,c);
        if ((lane&15)==0){
          int g = lane>>4;
          #pragma unroll
          for (int i2=0;i2<4;++i2) yeb[mt*16 + g*4 + i2] = c[i2];
        }
      }
      __syncthreads();
      // ---- phase 10: cvE ----
      {
        float ye = yeb[lane] + eboS;
        cvE = fmaf(coef, ye, cvE);
      }

      if (ii==PER){
        // G -> Hb0 cols 0..31 (raw, bf16); stash Snew & C per sample
        if (wid==0){ Sb[lane]=S; Cb[lane]=C; }
        stD(Hb0, ntv*16, mtv, lane, G, 0.0f, false);
        __syncthreads();
        // RR += G @ vWo + C (x) vbo ; then maturity pr stats
        const float disc_i = expf(-RRATE*t1);
        #pragma unroll
        for (int q=0;q<3;++q){
          const int T = wid*3+q;
          const int mtr = T/6, ntr = T%6;
          short8 a = rdA(Hb0, mtr, 0, lane);
          const int col = ntr*16 + (lane&15);
          short8 bw;
          #pragma unroll
          for (int i2=0;i2<8;++i2){
            int k = ((lane>>4)<<3)+i2;
            float w = (k<30 && col<84) ? vWop[k*84 + col] : 0.0f;
            bw[i2] = (short)f2bf(w);
          }
          f32x4 d={0.f,0.f,0.f,0.f};
          d = mm(a, bw, d);
          float vb  = (col<84) ? vbop[col] : 0.0f;
          bool inr  = (col >= p*NSTR) && (col < p*NSTR + NSTR);
          float K   = strikef(col - p*NSTR);
          float ssum=0.f, ssq=0.f;
          #pragma unroll
          for (int i2=0;i2<4;++i2){
            int r = mtr*16 + ((lane>>4)<<2) + i2;
            rr[q][i2] += d[i2] + Cb[r]*vb;
            if (inr){
              float pr = disc_i * fmaxf(Sb[r] - K, 0.f) - rr[q][i2];
              ssum += pr; ssq = fmaf(pr, pr, ssq);
            }
          }
          ssum += __shfl_down(ssum,16); ssum += __shfl_down(ssum,32);
          ssq  += __shfl_down(ssq ,16); ssq  += __shfl_down(ssq ,32);
          if (inr && lane < 16){
            int s = col - p*NSTR;
            part[(mtr*NSTR+s)*2+0] = ssum;
            part[(mtr*NSTR+s)*2+1] = ssq;
          }
        }
        __syncthreads();
        if (tid < NSTR){
          float s4 = part[(0*NSTR+tid)*2]+part[(1*NSTR+tid)*2]
                   + part[(2*NSTR+tid)*2]+part[(3*NSTR+tid)*2];
          ws[WS_PRPART + ((p*NSTR+tid)*2+0)*256 + blockIdx.x] = s4;
        } else if (tid >= 64 && tid < 64+NSTR){
          int s = tid-64;
          float q4 = part[(0*NSTR+s)*2+1]+part[(1*NSTR+s)*2+1]
                   + part[(2*NSTR+s)*2+1]+part[(3*NSTR+s)*2+1];
          ws[WS_PRPART + ((p*NSTR+s)*2+1)*256 + blockIdx.x] = q4;
        }
        #pragma unroll
        for (int i2=0;i2<4;++i2) G[i2]=0.f;
        C = 0.0f;
        __syncthreads();
      }
    }
  }

  if (wid==0){
    const float discT = expf(-RRATE*1.0f);
    const float e  = discT * (runmax - S);
    const float pe = e - cvE;
    out[OUT_PEXO + m] = pe;
    float se = e;
    for (int o=32;o>0;o>>=1) se += __shfl_down(se,o);
    if (lane==0) ws[WS_EPART + blockIdx.x] = se;
  }
}

extern "C" __global__ void fin_pv(const float* __restrict__ ws, float* __restrict__ out){
  const int t = threadIdx.x;
  if (t >= NMAT*NSTR) return;
  float sum=0.0f, ssq=0.0f;
  for (int b=0;b<256;++b){
    sum += ws[WS_PRPART + (t*2+0)*256 + b];
    ssq += ws[WS_PRPART + (t*2+1)*256 + b];
  }
  out[OUT_PV  + t] = sum * (1.0f/MC);
  out[OUT_PVV + t] = (ssq - sum*sum*(1.0f/MC)) * (1.0f/(MC-1));
}

extern "C" __global__ void fin_pe(float* out, float* ws){
  __shared__ float sA[4], sB[4], sC[4];
  const int t = threadIdx.x;
  float sum=0.0f, ssq=0.0f;
  for (int idx=t; idx<MC; idx+=256){
    const float v = out[OUT_PEXO+idx];
    sum += v; ssq = fmaf(v,v,ssq);
  }
  float es = ws[WS_EPART + t];
  for (int o=32;o>0;o>>=1){
    sum += __shfl_down(sum,o);
    ssq += __shfl_down(ssq,o);
    es  += __shfl_down(es,o);
  }
  const int w=t>>6, lane=t&63;
  if (lane==0){ sA[w]=sum; sB[w]=ssq; sC[w]=es; }
  __syncthreads();
  if (t==0){
    const float s=sA[0]+sA[1]+sA[2]+sA[3];
    const float q=sB[0]+sB[1]+sB[2]+sB[3];
    const float e=sC[0]+sC[1]+sC[2]+sC[3];
    out[OUT_MEAN]=s*(1.0f/MC);
    out[OUT_VAR]=(q - s*s*(1.0f/MC))*(1.0f/(MC-1));
    ws[WS_MEANE]=e*(1.0f/MC);
  }
}

extern "C" __global__ void fin_err(float* out, const float* __restrict__ ws){
  const int m = blockIdx.x*blockDim.x + threadIdx.x;
  if (m < MC) out[OUT_ERR+m] = out[OUT_PEXO+m] - ws[WS_MEANE];
}

extern "C" void kernel_launch(void* const* d_in, const int* in_sizes, int n_in,
                              void* d_out, int out_size, void* d_ws, size_t ws_size,
                              hipStream_t stream){
  (void)in_sizes; (void)n_in; (void)out_size; (void)ws_size;
  const float* S0 =(const float*)d_in[0];
  const float* z  =(const float*)d_in[1];
  const float* dW0=(const float*)d_in[2];
  const float* db0=(const float*)d_in[3];
  const float* dhW=(const float*)d_in[4];
  const float* dhb=(const float*)d_in[5];
  const float* dWo=(const float*)d_in[6];
  const float* dbo=(const float*)d_in[7];
  const float* vW0=(const float*)d_in[8];
  const float* vb0=(const float*)d_in[9];
  const float* vhW=(const float*)d_in[10];
  const float* vhb=(const float*)d_in[11];
  const float* vWo=(const float*)d_in[12];
  const float* vbo=(const float*)d_in[13];
  const float* eW0=(const float*)d_in[14];
  const float* eb0=(const float*)d_in[15];
  const float* ehW=(const float*)d_in[16];
  const float* ehb=(const float*)d_in[17];
  const float* eWo=(const float*)d_in[18];
  const float* ebo=(const float*)d_in[19];
  float* out=(float*)d_out;
  float* ws =(float*)d_ws;

  mc_main<<<dim3(256),dim3(512),0,stream>>>(S0,z,dW0,db0,dhW,dhb,dWo,dbo,
                                            vW0,vb0,vhW,vhb,vWo,vbo,
                                            eW0,eb0,ehW,ehb,eWo,ebo,out,ws);
  fin_pv <<<dim3(1), dim3(128),0,stream>>>(ws,out);
  fin_pe <<<dim3(1), dim3(256),0,stream>>>(out,ws);
  fin_err<<<dim3(64),dim3(256),0,stream>>>(out,ws);
}